// Round 10
// baseline (91.221 us; speedup 1.0000x reference)
//
#include <hip/hip_runtime.h>

#define NN 50
#define D 64
#define GRP 10
#define EM 8   // elements per wave in the MLP kernel

typedef unsigned int uint32;
typedef unsigned short ushort16;

__device__ __forceinline__ float wave_sum64(float x) {
#pragma unroll
  for (int off = 32; off > 0; off >>= 1)
    x += __shfl_xor(x, off, 64);
  return x;
}

__device__ __forceinline__ float readlane_f(float v, int l) {
  return __uint_as_float(__builtin_amdgcn_readlane(__float_as_uint(v), l));
}

__device__ __forceinline__ ushort16 f32_to_bf16(float f) {
  uint32 u = __float_as_uint(f);
  u += 0x7FFF + ((u >> 16) & 1);          // round-to-nearest-even
  return (ushort16)(u >> 16);
}
__device__ __forceinline__ float bf16_to_f32(ushort16 h) {
  return __uint_as_float(((uint32)h) << 16);
}

// ============ P: proj[e] = dot(ent[e], Wn); ent_bf = bf16(ent) ==============
__global__ __launch_bounds__(256, 4) void ent_proj(
    const float* __restrict__ ent_tab, const float* __restrict__ attn_W,
    float* __restrict__ proj, ushort16* __restrict__ ent_bf, int rows)
{
  const int  lane = threadIdx.x & 63;
  const long wave = (long)blockIdx.x * 4 + (threadIdx.x >> 6);
  const long base = wave * GRP;
  if (base >= rows) return;
  const float Wn = attn_W[D + lane];
  float v[GRP];
#pragma unroll
  for (int i = 0; i < GRP; ++i) {
    long r = base + i; if (r > rows - 1) r = rows - 1;
    v[i] = ent_tab[r * D + lane];           // coalesced, contiguous rows
  }
  float s[GRP];
#pragma unroll
  for (int i = 0; i < GRP; ++i)
    s[i] = wave_sum64(v[i] * Wn);           // 10 independent butterfly chains
#pragma unroll
  for (int i = 0; i < GRP; ++i) {
    const long r = base + i;
    if (r < rows) ent_bf[r * D + lane] = f32_to_bf16(v[i]);
  }
  if (lane == 0) {
#pragma unroll
    for (int i = 0; i < GRP; ++i)
      if (base + i < rows) proj[base + i] = s[i];
  }
}

// ===================== A: attention -> na rows in ws ========================
__device__ __forceinline__ void load_grp_bf(float (&buf)[GRP],
                                            const int* __restrict__ adjb,
                                            const ushort16* __restrict__ ent_bf,
                                            int g, int lane) {
#pragma unroll
  for (int i = 0; i < GRP; ++i) {
    int t = adjb[g * GRP + i];              // wave-uniform -> s_load
    t = t < 0 ? 0 : t;
    buf[i] = bf16_to_f32(ent_bf[(long)t * D + lane]);   // 128B coalesced row
  }
}

__device__ __forceinline__ void acc_grp(const float (&buf)[GRP], float e, int g,
                                        float& na0, float& na1) {
#pragma unroll
  for (int i = 0; i < GRP; ++i) {
    const float w = readlane_f(e, g * GRP + i);   // compile-time lane index
    if (i & 1) na1 = fmaf(w, buf[i], na1);
    else       na0 = fmaf(w, buf[i], na0);
  }
}

__global__ __launch_bounds__(256, 4) void kgat_attn(
    const int* __restrict__ item_idx, const int* __restrict__ adj,
    const float* __restrict__ item_tab,
    const ushort16* __restrict__ ent_bf, const float* __restrict__ proj,
    const float* __restrict__ attn_W, const float* __restrict__ attn_b,
    float* __restrict__ naws, int B)
{
  const int lane = threadIdx.x & 63;
  const int wv   = threadIdx.x >> 6;
  const int b    = blockIdx.x * 4 + wv;
  if (b >= B) return;

  const int* adjb = adj + (long)b * NN;

  // issue first two gather groups before score math (overlap latency)
  float A[GRP], Bv[GRP];
  load_grp_bf(A,  adjb, ent_bf, 0, lane);
  load_grp_bf(Bv, adjb, ent_bf, 1, lane);

  const float item = item_tab[(long)item_idx[b] * D + lane];
  const float base = wave_sum64(item * attn_W[lane]) + attn_b[0];  // uniform

  // scores: lane n gathers proj[adj[n]] (800KB, L2-hot); fixed-max softmax
  const int myn = lane < NN ? lane : NN - 1;
  int mi = adjb[myn]; mi = mi < 0 ? 0 : mi;
  float s = proj[mi] + base;
  s = s > 0.f ? s : 0.2f * s;                     // leaky_relu(0.2)
  const float e = (lane < NN) ? __expf(s - 8.0f) : 0.f;
  const float denom = wave_sum64(e);

  // weighted sum: proven double-buffered coalesced row groups (bf16 rows)
  float na0 = 0.f, na1 = 0.f;
  acc_grp(A,  e, 0, na0, na1);
  load_grp_bf(A,  adjb, ent_bf, 2, lane);
  acc_grp(Bv, e, 1, na0, na1);
  load_grp_bf(Bv, adjb, ent_bf, 3, lane);
  acc_grp(A,  e, 2, na0, na1);
  load_grp_bf(A,  adjb, ent_bf, 4, lane);
  acc_grp(Bv, e, 3, na0, na1);
  acc_grp(A,  e, 4, na0, na1);

  naws[(long)b * D + lane] = (na0 + na1) / denom;
}

// ================= M: MLP chain, 8 elements per wave ========================
__global__ __launch_bounds__(256, 2) void kgat_mlp(
    const int* __restrict__ user_idx, const int* __restrict__ item_idx,
    const float* __restrict__ user_tab, const float* __restrict__ item_tab,
    const float* __restrict__ naws,
    const float* __restrict__ W1, const float* __restrict__ b1,
    const float* __restrict__ W2, const float* __restrict__ b2,
    const float* __restrict__ cW, const float* __restrict__ cb,
    const float* __restrict__ oW, const float* __restrict__ ob,
    float* __restrict__ out, int B)
{
  const int lane = threadIdx.x & 63;
  const int wv   = threadIdx.x >> 6;
  const int b0   = (blockIdx.x * 4 + wv) * EM;
  if (b0 >= B) return;

  float na[EM], it[EM], us[EM];
#pragma unroll
  for (int e = 0; e < EM; ++e) {
    int b = b0 + e; b = b < B ? b : B - 1;
    na[e] = naws[(long)b * D + lane];
    it[e] = item_tab[(long)item_idx[b] * D + lane];
    us[e] = user_tab[(long)user_idx[b] * D + lane];
  }

  float a0[EM], a1[EM];

  // ---- h = relu(na @ W1 + b1): weight column loaded ONCE per 8 elements ----
  const float b1v = b1[lane];
#pragma unroll
  for (int e = 0; e < EM; ++e) { a0[e] = b1v; a1[e] = 0.f; }
#pragma unroll
  for (int d = 0; d < D; d += 2) {
    const float w0 = W1[(d + 0) * D + lane];
    const float w1 = W1[(d + 1) * D + lane];
#pragma unroll
    for (int e = 0; e < EM; ++e) {
      a0[e] = fmaf(readlane_f(na[e], d + 0), w0, a0[e]);
      a1[e] = fmaf(readlane_f(na[e], d + 1), w1, a1[e]);
    }
  }
  float h[EM];
#pragma unroll
  for (int e = 0; e < EM; ++e) h[e] = fmaxf(a0[e] + a1[e], 0.f);

  // ---- r = h @ W2 + b2 ----
  const float b2v = b2[lane];
#pragma unroll
  for (int e = 0; e < EM; ++e) { a0[e] = b2v; a1[e] = 0.f; }
#pragma unroll
  for (int d = 0; d < D; d += 2) {
    const float w0 = W2[(d + 0) * D + lane];
    const float w1 = W2[(d + 1) * D + lane];
#pragma unroll
    for (int e = 0; e < EM; ++e) {
      a0[e] = fmaf(readlane_f(h[e], d + 0), w0, a0[e]);
      a1[e] = fmaf(readlane_f(h[e], d + 1), w1, a1[e]);
    }
  }
  float r[EM];
#pragma unroll
  for (int e = 0; e < EM; ++e) r[e] = a0[e] + a1[e];

  // ---- f = relu([item, r] @ cW + cb) ----
  const float cbv = cb[lane];
#pragma unroll
  for (int e = 0; e < EM; ++e) { a0[e] = cbv; a1[e] = 0.f; }
#pragma unroll
  for (int k = 0; k < D; k += 2) {
    const float w0 = cW[(k + 0) * D + lane];
    const float w1 = cW[(k + 1) * D + lane];
#pragma unroll
    for (int e = 0; e < EM; ++e) {
      a0[e] = fmaf(readlane_f(it[e], k + 0), w0, a0[e]);
      a1[e] = fmaf(readlane_f(it[e], k + 1), w1, a1[e]);
    }
  }
#pragma unroll
  for (int k = 0; k < D; k += 2) {
    const float w0 = cW[(D + k + 0) * D + lane];
    const float w1 = cW[(D + k + 1) * D + lane];
#pragma unroll
    for (int e = 0; e < EM; ++e) {
      a0[e] = fmaf(readlane_f(r[e], k + 0), w0, a0[e]);
      a1[e] = fmaf(readlane_f(r[e], k + 1), w1, a1[e]);
    }
  }

  // ---- score = dot([user, f], oW) + ob ----
  const float oWu = oW[lane];
  const float oWf = oW[D + lane];
  const float ob0 = ob[0];
#pragma unroll
  for (int e = 0; e < EM; ++e) {
    const float f  = fmaxf(a0[e] + a1[e], 0.f);
    const float sc = wave_sum64(fmaf(us[e], oWu, f * oWf));
    const int b = b0 + e;
    if (lane == 0 && b < B) out[b] = sc + ob0;
  }
}

// ================= fallback: exact R3 kernel (small/no workspace) ===========
__device__ __forceinline__ void load_grp(float (&buf)[GRP],
                                         const int* __restrict__ adjb,
                                         const float* __restrict__ ent_tab,
                                         int g, int lane) {
#pragma unroll
  for (int i = 0; i < GRP; ++i) {
    int t = adjb[g * GRP + i];
    t = t < 0 ? 0 : t;
    buf[i] = ent_tab[(long)t * D + lane];
  }
}

__device__ __forceinline__ void proc_grp(const float (&buf)[GRP],
                                         float Wn, float base,
                                         float& l0, float& l1, float& na) {
  float ex[GRP];
#pragma unroll
  for (int i = 0; i < GRP; ++i) {
    float t = wave_sum64(buf[i] * Wn) + base;
    t = t > 0.f ? t : 0.2f * t;
    ex[i] = __expf(t - 8.0f);
  }
#pragma unroll
  for (int i = 0; i < GRP; ++i) {
    if (i & 1) l1 += ex[i]; else l0 += ex[i];
    na = fmaf(ex[i], buf[i], na);
  }
}

__global__ __launch_bounds__(256, 4) void kgat_r3(
    const int* __restrict__ user_idx, const int* __restrict__ item_idx,
    const int* __restrict__ adj,
    const float* __restrict__ user_tab, const float* __restrict__ item_tab,
    const float* __restrict__ ent_tab,
    const float* __restrict__ attn_W, const float* __restrict__ attn_b,
    const float* __restrict__ W1, const float* __restrict__ b1,
    const float* __restrict__ W2, const float* __restrict__ b2,
    const float* __restrict__ cW, const float* __restrict__ cb,
    const float* __restrict__ oW, const float* __restrict__ ob,
    float* __restrict__ out, int B)
{
  const int lane = threadIdx.x & 63;
  const int wv   = threadIdx.x >> 6;
  const int b    = blockIdx.x * 4 + wv;
  if (b >= B) return;

  const float user = user_tab[(long)user_idx[b] * D + lane];
  const float oWu  = oW[lane];
  const float oWf  = oW[D + lane];
  const float item = item_tab[(long)item_idx[b] * D + lane];
  const float Wi   = attn_W[lane];
  const float Wn   = attn_W[D + lane];
  const float base = wave_sum64(item * Wi) + attn_b[0];
  const int* adjb = adj + b * NN;

  float na = 0.f, l0 = 0.f, l1 = 0.f;
  float A[GRP], Bv[GRP];
  load_grp(A,  adjb, ent_tab, 0, lane);
  load_grp(Bv, adjb, ent_tab, 1, lane);
  proc_grp(A,  Wn, base, l0, l1, na);
  load_grp(A,  adjb, ent_tab, 2, lane);
  proc_grp(Bv, Wn, base, l0, l1, na);
  load_grp(Bv, adjb, ent_tab, 3, lane);
  proc_grp(A,  Wn, base, l0, l1, na);
  load_grp(A,  adjb, ent_tab, 4, lane);
  proc_grp(Bv, Wn, base, l0, l1, na);
  proc_grp(A,  Wn, base, l0, l1, na);
  na /= (l0 + l1);

  float h0 = b1[lane], h1 = 0.f, h2 = 0.f, h3 = 0.f;
#pragma unroll
  for (int d = 0; d < D; d += 4) {
    h0 = fmaf(readlane_f(na, d + 0), W1[(d + 0) * D + lane], h0);
    h1 = fmaf(readlane_f(na, d + 1), W1[(d + 1) * D + lane], h1);
    h2 = fmaf(readlane_f(na, d + 2), W1[(d + 2) * D + lane], h2);
    h3 = fmaf(readlane_f(na, d + 3), W1[(d + 3) * D + lane], h3);
  }
  const float h = fmaxf((h0 + h1) + (h2 + h3), 0.f);

  float r0 = b2[lane], r1 = 0.f, r2 = 0.f, r3 = 0.f;
#pragma unroll
  for (int d = 0; d < D; d += 4) {
    r0 = fmaf(readlane_f(h, d + 0), W2[(d + 0) * D + lane], r0);
    r1 = fmaf(readlane_f(h, d + 1), W2[(d + 1) * D + lane], r1);
    r2 = fmaf(readlane_f(h, d + 2), W2[(d + 2) * D + lane], r2);
    r3 = fmaf(readlane_f(h, d + 3), W2[(d + 3) * D + lane], r3);
  }
  const float r = (r0 + r1) + (r2 + r3);

  float f0 = cb[lane], f1 = 0.f, f2 = 0.f, f3 = 0.f;
#pragma unroll
  for (int k = 0; k < D; k += 4) {
    f0 = fmaf(readlane_f(item, k + 0), cW[(k + 0) * D + lane], f0);
    f1 = fmaf(readlane_f(item, k + 1), cW[(k + 1) * D + lane], f1);
    f2 = fmaf(readlane_f(item, k + 2), cW[(k + 2) * D + lane], f2);
    f3 = fmaf(readlane_f(item, k + 3), cW[(k + 3) * D + lane], f3);
  }
#pragma unroll
  for (int k = 0; k < D; k += 4) {
    f0 = fmaf(readlane_f(r, k + 0), cW[(D + k + 0) * D + lane], f0);
    f1 = fmaf(readlane_f(r, k + 1), cW[(D + k + 1) * D + lane], f1);
    f2 = fmaf(readlane_f(r, k + 2), cW[(D + k + 2) * D + lane], f2);
    f3 = fmaf(readlane_f(r, k + 3), cW[(D + k + 3) * D + lane], f3);
  }
  const float f = fmaxf((f0 + f1) + (f2 + f3), 0.f);

  const float sc = wave_sum64(fmaf(user, oWu, f * oWf));
  if (lane == 0) out[b] = sc + ob[0];
}

extern "C" void kernel_launch(void* const* d_in, const int* in_sizes, int n_in,
                              void* d_out, int out_size, void* d_ws, size_t ws_size,
                              hipStream_t stream) {
  const int*   user_idx = (const int*)d_in[0];
  const int*   item_idx = (const int*)d_in[1];
  const int*   adj      = (const int*)d_in[2];
  const float* user_tab = (const float*)d_in[3];
  const float* item_tab = (const float*)d_in[4];
  const float* ent_tab  = (const float*)d_in[5];
  const float* attn_W   = (const float*)d_in[6];
  const float* attn_b   = (const float*)d_in[7];
  const float* W1       = (const float*)d_in[8];
  const float* b1       = (const float*)d_in[9];
  const float* W2       = (const float*)d_in[10];
  const float* b2       = (const float*)d_in[11];
  const float* cW       = (const float*)d_in[12];
  const float* cb       = (const float*)d_in[13];
  const float* oW       = (const float*)d_in[14];
  const float* ob       = (const float*)d_in[15];
  float* out = (float*)d_out;

  const int B    = in_sizes[0];
  const int rows = in_sizes[5] / D;               // entity count

  // ws layout: [proj f32][ent_bf bf16][na f32], 256B-aligned sections
  const size_t off_bf = ((size_t)rows * 4 + 255) & ~(size_t)255;
  const size_t off_na = (off_bf + (size_t)rows * D * 2 + 255) & ~(size_t)255;
  const size_t need   = off_na + (size_t)B * D * 4;

  const int blocks = (B + 3) / 4;

  if (ws_size >= need) {
    float*    proj   = (float*)d_ws;
    ushort16* ent_bf = (ushort16*)((char*)d_ws + off_bf);
    float*    naws   = (float*)((char*)d_ws + off_na);
    const int waves   = (rows + GRP - 1) / GRP;
    const int pblocks = (waves + 3) / 4;
    const int mblocks = (B + 4 * EM - 1) / (4 * EM);
    ent_proj<<<pblocks, 256, 0, stream>>>(ent_tab, attn_W, proj, ent_bf, rows);
    kgat_attn<<<blocks, 256, 0, stream>>>(item_idx, adj, item_tab, ent_bf,
                                          proj, attn_W, attn_b, naws, B);
    kgat_mlp<<<mblocks, 256, 0, stream>>>(user_idx, item_idx, user_tab,
                                          item_tab, naws, W1, b1, W2, b2,
                                          cW, cb, oW, ob, out, B);
  } else {
    kgat_r3<<<blocks, 256, 0, stream>>>(user_idx, item_idx, adj,
                                        user_tab, item_tab, ent_tab,
                                        attn_W, attn_b, W1, b1, W2, b2,
                                        cW, cb, oW, ob, out, B);
  }
}

// Round 11
// 71.875 us; speedup vs baseline: 1.2692x; 1.2692x over previous
//
#include <hip/hip_runtime.h>

#define NN 50
#define D 64
#define GRP 10

typedef unsigned int uint32;
typedef unsigned short ushort16;

__device__ __forceinline__ float wave_sum64(float x) {
#pragma unroll
  for (int off = 32; off > 0; off >>= 1)
    x += __shfl_xor(x, off, 64);
  return x;
}

__device__ __forceinline__ float readlane_f(float v, int l) {
  return __uint_as_float(__builtin_amdgcn_readlane(__float_as_uint(v), l));
}

__device__ __forceinline__ ushort16 f32_to_bf16(float f) {
  uint32 u = __float_as_uint(f);
  u += 0x7FFF + ((u >> 16) & 1);          // round-to-nearest-even
  return (ushort16)(u >> 16);
}
__device__ __forceinline__ float bf16_to_f32(ushort16 h) {
  return __uint_as_float(((uint32)h) << 16);
}

// ============ P: proj[e] = dot(ent[e], Wn); ent_bf = bf16(ent) ==============
__global__ __launch_bounds__(256, 4) void ent_proj(
    const float* __restrict__ ent_tab, const float* __restrict__ attn_W,
    float* __restrict__ proj, ushort16* __restrict__ ent_bf, int rows)
{
  const int  lane = threadIdx.x & 63;
  const long wave = (long)blockIdx.x * 4 + (threadIdx.x >> 6);
  const long base = wave * GRP;
  if (base >= rows) return;
  const float Wn = attn_W[D + lane];
  float v[GRP];
#pragma unroll
  for (int i = 0; i < GRP; ++i) {
    long r = base + i; if (r > rows - 1) r = rows - 1;
    v[i] = ent_tab[r * D + lane];           // coalesced, contiguous rows
  }
  float s[GRP];
#pragma unroll
  for (int i = 0; i < GRP; ++i)
    s[i] = wave_sum64(v[i] * Wn);           // 10 independent butterfly chains
#pragma unroll
  for (int i = 0; i < GRP; ++i) {
    const long r = base + i;
    if (r < rows) ent_bf[r * D + lane] = f32_to_bf16(v[i]);
  }
  if (lane == 0) {
#pragma unroll
    for (int i = 0; i < GRP; ++i)
      if (base + i < rows) proj[base + i] = s[i];
  }
}

// ================== fused attn + MLP (R9 kgat_main + bf16 gathers) ==========
__device__ __forceinline__ void load_grp_bf(float (&buf)[GRP],
                                            const int* __restrict__ adjb,
                                            const ushort16* __restrict__ ent_bf,
                                            int g, int lane) {
#pragma unroll
  for (int i = 0; i < GRP; ++i) {
    int t = adjb[g * GRP + i];              // wave-uniform -> s_load
    t = t < 0 ? 0 : t;
    buf[i] = bf16_to_f32(ent_bf[(long)t * D + lane]);   // 128B coalesced row
  }
}

__device__ __forceinline__ void acc_grp(const float (&buf)[GRP], float e, int g,
                                        float& na0, float& na1) {
#pragma unroll
  for (int i = 0; i < GRP; ++i) {
    const float w = readlane_f(e, g * GRP + i);   // compile-time lane index
    if (i & 1) na1 = fmaf(w, buf[i], na1);
    else       na0 = fmaf(w, buf[i], na0);
  }
}

__global__ __launch_bounds__(256, 4) void kgat_fused(
    const int* __restrict__ user_idx, const int* __restrict__ item_idx,
    const int* __restrict__ adj,
    const float* __restrict__ user_tab, const float* __restrict__ item_tab,
    const ushort16* __restrict__ ent_bf, const float* __restrict__ proj,
    const float* __restrict__ attn_W, const float* __restrict__ attn_b,
    const float* __restrict__ W1, const float* __restrict__ b1,
    const float* __restrict__ W2, const float* __restrict__ b2,
    const float* __restrict__ cW, const float* __restrict__ cb,
    const float* __restrict__ oW, const float* __restrict__ ob,
    float* __restrict__ out, int B)
{
  __shared__ __align__(16) float s_act[4 * D];   // per-wave activation bcast
  __shared__ __align__(16) float s_itm[4 * D];   // per-wave item bcast

  const int lane = threadIdx.x & 63;
  const int wv   = threadIdx.x >> 6;
  const int b    = blockIdx.x * 4 + wv;
  if (b >= B) return;
  float* sa = s_act + wv * D;
  float* si = s_itm + wv * D;

  const int* adjb = adj + (long)b * NN;

  // issue first two gather groups before score math (overlap latency)
  float A[GRP], Bv[GRP];
  load_grp_bf(A,  adjb, ent_bf, 0, lane);
  load_grp_bf(Bv, adjb, ent_bf, 1, lane);

  const float user = user_tab[(long)user_idx[b] * D + lane];
  const float item = item_tab[(long)item_idx[b] * D + lane];
  si[lane] = item;                                // wave-private, no barrier
  const float base = wave_sum64(item * attn_W[lane]) + attn_b[0];  // uniform

  // ---- scores: lane n gathers proj[adj[n]] (800KB, L2-hot) ----
  const int myn = lane < NN ? lane : NN - 1;
  int mi = adjb[myn]; mi = mi < 0 ? 0 : mi;
  float s = proj[mi] + base;
  s = s > 0.f ? s : 0.2f * s;                     // leaky_relu(0.2)
  // fixed-max softmax: scores are leaky_relu of ~unit-variance dots, bounded
  // well below 8 -> exp(s-8) can't overflow, denom can't underflow to 0.
  const float e = (lane < NN) ? __expf(s - 8.0f) : 0.f;
  const float denom = wave_sum64(e);

  // ---- weighted sum: proven double-buffered coalesced bf16 row groups ----
  float na0 = 0.f, na1 = 0.f;
  acc_grp(A,  e, 0, na0, na1);
  load_grp_bf(A,  adjb, ent_bf, 2, lane);
  acc_grp(Bv, e, 1, na0, na1);
  load_grp_bf(Bv, adjb, ent_bf, 3, lane);
  acc_grp(A,  e, 2, na0, na1);
  load_grp_bf(A,  adjb, ent_bf, 4, lane);
  acc_grp(Bv, e, 3, na0, na1);
  acc_grp(A,  e, 4, na0, na1);
  const float na = (na0 + na1) / denom;

  // ---- h = relu(na @ W1 + b1): activations broadcast from LDS (b128,
  //      uniform address = conflict-free), weights coalesced from global ----
  sa[lane] = na;
  float h0 = b1[lane], h1 = 0.f, h2 = 0.f, h3 = 0.f;
#pragma unroll
  for (int d = 0; d < D; d += 4) {
    const float4 c = *(const float4*)(sa + d);
    h0 = fmaf(c.x, W1[(d + 0) * D + lane], h0);
    h1 = fmaf(c.y, W1[(d + 1) * D + lane], h1);
    h2 = fmaf(c.z, W1[(d + 2) * D + lane], h2);
    h3 = fmaf(c.w, W1[(d + 3) * D + lane], h3);
  }
  const float h = fmaxf((h0 + h1) + (h2 + h3), 0.f);

  // ---- r = h @ W2 + b2 ----
  sa[lane] = h;
  float r0 = b2[lane], r1 = 0.f, r2 = 0.f, r3 = 0.f;
#pragma unroll
  for (int d = 0; d < D; d += 4) {
    const float4 c = *(const float4*)(sa + d);
    r0 = fmaf(c.x, W2[(d + 0) * D + lane], r0);
    r1 = fmaf(c.y, W2[(d + 1) * D + lane], r1);
    r2 = fmaf(c.z, W2[(d + 2) * D + lane], r2);
    r3 = fmaf(c.w, W2[(d + 3) * D + lane], r3);
  }
  const float r = (r0 + r1) + (r2 + r3);

  // ---- f = relu([item, r] @ cW + cb) ----
  sa[lane] = r;
  float f0 = cb[lane], f1 = 0.f, f2 = 0.f, f3 = 0.f;
#pragma unroll
  for (int k = 0; k < D; k += 4) {
    const float4 ci = *(const float4*)(si + k);
    f0 = fmaf(ci.x, cW[(k + 0) * D + lane], f0);
    f1 = fmaf(ci.y, cW[(k + 1) * D + lane], f1);
    f2 = fmaf(ci.z, cW[(k + 2) * D + lane], f2);
    f3 = fmaf(ci.w, cW[(k + 3) * D + lane], f3);
  }
#pragma unroll
  for (int k = 0; k < D; k += 4) {
    const float4 cr = *(const float4*)(sa + k);
    f0 = fmaf(cr.x, cW[(D + k + 0) * D + lane], f0);
    f1 = fmaf(cr.y, cW[(D + k + 1) * D + lane], f1);
    f2 = fmaf(cr.z, cW[(D + k + 2) * D + lane], f2);
    f3 = fmaf(cr.w, cW[(D + k + 3) * D + lane], f3);
  }
  const float f = fmaxf((f0 + f1) + (f2 + f3), 0.f);

  // ---- score = dot([user, f], oW) + ob ----
  const float sc = wave_sum64(fmaf(user, oW[lane], f * oW[D + lane]));
  if (lane == 0) out[b] = sc + ob[0];
}

// ================= fallback: exact R3 kernel (small/no workspace) ===========
__device__ __forceinline__ void load_grp(float (&buf)[GRP],
                                         const int* __restrict__ adjb,
                                         const float* __restrict__ ent_tab,
                                         int g, int lane) {
#pragma unroll
  for (int i = 0; i < GRP; ++i) {
    int t = adjb[g * GRP + i];
    t = t < 0 ? 0 : t;
    buf[i] = ent_tab[(long)t * D + lane];
  }
}

__device__ __forceinline__ void proc_grp(const float (&buf)[GRP],
                                         float Wn, float base,
                                         float& l0, float& l1, float& na) {
  float ex[GRP];
#pragma unroll
  for (int i = 0; i < GRP; ++i) {
    float t = wave_sum64(buf[i] * Wn) + base;
    t = t > 0.f ? t : 0.2f * t;
    ex[i] = __expf(t - 8.0f);
  }
#pragma unroll
  for (int i = 0; i < GRP; ++i) {
    if (i & 1) l1 += ex[i]; else l0 += ex[i];
    na = fmaf(ex[i], buf[i], na);
  }
}

__global__ __launch_bounds__(256, 4) void kgat_r3(
    const int* __restrict__ user_idx, const int* __restrict__ item_idx,
    const int* __restrict__ adj,
    const float* __restrict__ user_tab, const float* __restrict__ item_tab,
    const float* __restrict__ ent_tab,
    const float* __restrict__ attn_W, const float* __restrict__ attn_b,
    const float* __restrict__ W1, const float* __restrict__ b1,
    const float* __restrict__ W2, const float* __restrict__ b2,
    const float* __restrict__ cW, const float* __restrict__ cb,
    const float* __restrict__ oW, const float* __restrict__ ob,
    float* __restrict__ out, int B)
{
  const int lane = threadIdx.x & 63;
  const int wv   = threadIdx.x >> 6;
  const int b    = blockIdx.x * 4 + wv;
  if (b >= B) return;

  const float user = user_tab[(long)user_idx[b] * D + lane];
  const float oWu  = oW[lane];
  const float oWf  = oW[D + lane];
  const float item = item_tab[(long)item_idx[b] * D + lane];
  const float Wi   = attn_W[lane];
  const float Wn   = attn_W[D + lane];
  const float base = wave_sum64(item * Wi) + attn_b[0];
  const int* adjb = adj + b * NN;

  float na = 0.f, l0 = 0.f, l1 = 0.f;
  float A[GRP], Bv[GRP];
  load_grp(A,  adjb, ent_tab, 0, lane);
  load_grp(Bv, adjb, ent_tab, 1, lane);
  proc_grp(A,  Wn, base, l0, l1, na);
  load_grp(A,  adjb, ent_tab, 2, lane);
  proc_grp(Bv, Wn, base, l0, l1, na);
  load_grp(Bv, adjb, ent_tab, 3, lane);
  proc_grp(A,  Wn, base, l0, l1, na);
  load_grp(A,  adjb, ent_tab, 4, lane);
  proc_grp(Bv, Wn, base, l0, l1, na);
  proc_grp(A,  Wn, base, l0, l1, na);
  na /= (l0 + l1);

  float h0 = b1[lane], h1 = 0.f, h2 = 0.f, h3 = 0.f;
#pragma unroll
  for (int d = 0; d < D; d += 4) {
    h0 = fmaf(readlane_f(na, d + 0), W1[(d + 0) * D + lane], h0);
    h1 = fmaf(readlane_f(na, d + 1), W1[(d + 1) * D + lane], h1);
    h2 = fmaf(readlane_f(na, d + 2), W1[(d + 2) * D + lane], h2);
    h3 = fmaf(readlane_f(na, d + 3), W1[(d + 3) * D + lane], h3);
  }
  const float h = fmaxf((h0 + h1) + (h2 + h3), 0.f);

  float r0 = b2[lane], r1 = 0.f, r2 = 0.f, r3 = 0.f;
#pragma unroll
  for (int d = 0; d < D; d += 4) {
    r0 = fmaf(readlane_f(h, d + 0), W2[(d + 0) * D + lane], r0);
    r1 = fmaf(readlane_f(h, d + 1), W2[(d + 1) * D + lane], r1);
    r2 = fmaf(readlane_f(h, d + 2), W2[(d + 2) * D + lane], r2);
    r3 = fmaf(readlane_f(h, d + 3), W2[(d + 3) * D + lane], r3);
  }
  const float r = (r0 + r1) + (r2 + r3);

  float f0 = cb[lane], f1 = 0.f, f2 = 0.f, f3 = 0.f;
#pragma unroll
  for (int k = 0; k < D; k += 4) {
    f0 = fmaf(readlane_f(item, k + 0), cW[(k + 0) * D + lane], f0);
    f1 = fmaf(readlane_f(item, k + 1), cW[(k + 1) * D + lane], f1);
    f2 = fmaf(readlane_f(item, k + 2), cW[(k + 2) * D + lane], f2);
    f3 = fmaf(readlane_f(item, k + 3), cW[(k + 3) * D + lane], f3);
  }
#pragma unroll
  for (int k = 0; k < D; k += 4) {
    f0 = fmaf(readlane_f(r, k + 0), cW[(D + k + 0) * D + lane], f0);
    f1 = fmaf(readlane_f(r, k + 1), cW[(D + k + 1) * D + lane], f1);
    f2 = fmaf(readlane_f(r, k + 2), cW[(D + k + 2) * D + lane], f2);
    f3 = fmaf(readlane_f(r, k + 3), cW[(D + k + 3) * D + lane], f3);
  }
  const float f = fmaxf((f0 + f1) + (f2 + f3), 0.f);

  const float sc = wave_sum64(fmaf(user, oWu, f * oWf));
  if (lane == 0) out[b] = sc + ob[0];
}

extern "C" void kernel_launch(void* const* d_in, const int* in_sizes, int n_in,
                              void* d_out, int out_size, void* d_ws, size_t ws_size,
                              hipStream_t stream) {
  const int*   user_idx = (const int*)d_in[0];
  const int*   item_idx = (const int*)d_in[1];
  const int*   adj      = (const int*)d_in[2];
  const float* user_tab = (const float*)d_in[3];
  const float* item_tab = (const float*)d_in[4];
  const float* ent_tab  = (const float*)d_in[5];
  const float* attn_W   = (const float*)d_in[6];
  const float* attn_b   = (const float*)d_in[7];
  const float* W1       = (const float*)d_in[8];
  const float* b1       = (const float*)d_in[9];
  const float* W2       = (const float*)d_in[10];
  const float* b2       = (const float*)d_in[11];
  const float* cW       = (const float*)d_in[12];
  const float* cb       = (const float*)d_in[13];
  const float* oW       = (const float*)d_in[14];
  const float* ob       = (const float*)d_in[15];
  float* out = (float*)d_out;

  const int B    = in_sizes[0];
  const int rows = in_sizes[5] / D;               // entity count

  // ws layout: [proj f32][ent_bf bf16], 256B-aligned sections
  const size_t off_bf = ((size_t)rows * 4 + 255) & ~(size_t)255;
  const size_t need   = off_bf + (size_t)rows * D * 2;

  const int blocks = (B + 3) / 4;

  if (ws_size >= need) {
    float*    proj   = (float*)d_ws;
    ushort16* ent_bf = (ushort16*)((char*)d_ws + off_bf);
    const int waves   = (rows + GRP - 1) / GRP;
    const int pblocks = (waves + 3) / 4;
    ent_proj<<<pblocks, 256, 0, stream>>>(ent_tab, attn_W, proj, ent_bf, rows);
    kgat_fused<<<blocks, 256, 0, stream>>>(user_idx, item_idx, adj,
                                           user_tab, item_tab, ent_bf, proj,
                                           attn_W, attn_b, W1, b1, W2, b2,
                                           cW, cb, oW, ob, out, B);
  } else {
    kgat_r3<<<blocks, 256, 0, stream>>>(user_idx, item_idx, adj,
                                        user_tab, item_tab, ent_tab,
                                        attn_W, attn_b, W1, b1, W2, b2,
                                        cW, cb, oW, ob, out, B);
  }
}